// Round 4
// baseline (376.174 us; speedup 1.0000x reference)
//
#include <hip/hip_runtime.h>
#include <math.h>

// Problem constants (reference: M, N = 8192, 8192; H = N/2)
#define M_ROWS 8192
#define N_COLS 8192
#define H_COLS 4096

// Native vector type — __builtin_nontemporal_* requires a real vector.
typedef float vf4 __attribute__((ext_vector_type(4)));

// Two rows per 512-thread block, software-pipelined:
//   issue ALL 8 loads/thread (rows r0,r1) up front (128 B in flight -> 4x MLP),
//   compute row0 (waits only r0's loads), reduce+barrier WHILE r1 loads are
//   still in flight, store row0, then compute/reduce/store row1.
// This keeps HBM traffic in flight across the block barrier, breaking the
// all-blocks-in-phase convoy that capped R3 at ~3.2 TB/s.
__global__ __launch_bounds__(512) void swiglu_quant_kernel(
    const float* __restrict__ x,
    const float* __restrict__ weight_scale,
    const float* __restrict__ activation_scale,
    const float* __restrict__ quant_scale,
    float* __restrict__ out_q,       // M*H floats (int8 values as f32)
    float* __restrict__ out_scale)   // M floats
{
    const int tid = threadIdx.x;
    const int r0  = blockIdx.x * 2;
    const int r1  = r0 + 1;

    const float w  = weight_scale[0];
    const float qs = quant_scale[0];
    const float c0 = w * activation_scale[r0];
    const float c1 = w * activation_scale[r1];
    const float a0 = qs * c0;   // folded: s = (qs*c*f) * (c*b) * sigmoid(c*b)
    const float a1 = qs * c1;

    const vf4* __restrict__ xf0 = (const vf4*)(x + (size_t)r0 * N_COLS);
    const vf4* __restrict__ xb0 = (const vf4*)(x + (size_t)r0 * N_COLS + H_COLS);
    const vf4* __restrict__ xf1 = (const vf4*)(x + (size_t)r1 * N_COLS);
    const vf4* __restrict__ xb1 = (const vf4*)(x + (size_t)r1 * N_COLS + H_COLS);

    // ---- issue all 8 loads (r0 first so compute can wait on vmcnt(4)) ----
    vf4 f0a = __builtin_nontemporal_load(&xf0[tid]);
    vf4 f0b = __builtin_nontemporal_load(&xf0[512 + tid]);
    vf4 b0a = __builtin_nontemporal_load(&xb0[tid]);
    vf4 b0b = __builtin_nontemporal_load(&xb0[512 + tid]);
    vf4 f1a = __builtin_nontemporal_load(&xf1[tid]);
    vf4 f1b = __builtin_nontemporal_load(&xf1[512 + tid]);
    vf4 b1a = __builtin_nontemporal_load(&xb1[tid]);
    vf4 b1b = __builtin_nontemporal_load(&xb1[512 + tid]);

    __shared__ float wmax[2][8];
    const int lane = tid & 63;
    const int wave = tid >> 6;

    // ---------------- row 0 ----------------
    float s0[8];
    float amax0 = 0.0f;
    #pragma unroll
    for (int k = 0; k < 4; ++k) {
        float g, v;
        g = c0 * b0a[k];
        v = (a0 * f0a[k]) * g * __builtin_amdgcn_rcpf(1.0f + __expf(-g));
        s0[k] = v; amax0 = fmaxf(amax0, fabsf(v));
        g = c0 * b0b[k];
        v = (a0 * f0b[k]) * g * __builtin_amdgcn_rcpf(1.0f + __expf(-g));
        s0[4 + k] = v; amax0 = fmaxf(amax0, fabsf(v));
    }
    #pragma unroll
    for (int off = 32; off > 0; off >>= 1)
        amax0 = fmaxf(amax0, __shfl_down(amax0, off, 64));
    if (lane == 0) wmax[0][wave] = amax0;
    __syncthreads();
    {
        float rowmax = wmax[0][0];
        #pragma unroll
        for (int wv = 1; wv < 8; ++wv) rowmax = fmaxf(rowmax, wmax[0][wv]);
        const float scale = rowmax * (1.0f / 127.0f);
        const float inv   = (scale > 0.0f) ? (127.0f / rowmax) : 0.0f;
        if (tid == 0) out_scale[r0] = scale;

        vf4* oq = (vf4*)(out_q + (size_t)r0 * H_COLS);
        vf4 o;
        #pragma unroll
        for (int k = 0; k < 4; ++k) {
            float q = rintf(s0[k] * inv);
            o[k] = fminf(fmaxf(q, -128.0f), 127.0f);
        }
        __builtin_nontemporal_store(o, &oq[tid]);
        #pragma unroll
        for (int k = 0; k < 4; ++k) {
            float q = rintf(s0[4 + k] * inv);
            o[k] = fminf(fmaxf(q, -128.0f), 127.0f);
        }
        __builtin_nontemporal_store(o, &oq[512 + tid]);
    }

    // ---------------- row 1 ----------------
    float s1[8];
    float amax1 = 0.0f;
    #pragma unroll
    for (int k = 0; k < 4; ++k) {
        float g, v;
        g = c1 * b1a[k];
        v = (a1 * f1a[k]) * g * __builtin_amdgcn_rcpf(1.0f + __expf(-g));
        s1[k] = v; amax1 = fmaxf(amax1, fabsf(v));
        g = c1 * b1b[k];
        v = (a1 * f1b[k]) * g * __builtin_amdgcn_rcpf(1.0f + __expf(-g));
        s1[4 + k] = v; amax1 = fmaxf(amax1, fabsf(v));
    }
    #pragma unroll
    for (int off = 32; off > 0; off >>= 1)
        amax1 = fmaxf(amax1, __shfl_down(amax1, off, 64));
    if (lane == 0) wmax[1][wave] = amax1;
    __syncthreads();
    {
        float rowmax = wmax[1][0];
        #pragma unroll
        for (int wv = 1; wv < 8; ++wv) rowmax = fmaxf(rowmax, wmax[1][wv]);
        const float scale = rowmax * (1.0f / 127.0f);
        const float inv   = (scale > 0.0f) ? (127.0f / rowmax) : 0.0f;
        if (tid == 0) out_scale[r1] = scale;

        vf4* oq = (vf4*)(out_q + (size_t)r1 * H_COLS);
        vf4 o;
        #pragma unroll
        for (int k = 0; k < 4; ++k) {
            float q = rintf(s1[k] * inv);
            o[k] = fminf(fmaxf(q, -128.0f), 127.0f);
        }
        __builtin_nontemporal_store(o, &oq[tid]);
        #pragma unroll
        for (int k = 0; k < 4; ++k) {
            float q = rintf(s1[4 + k] * inv);
            o[k] = fminf(fmaxf(q, -128.0f), 127.0f);
        }
        __builtin_nontemporal_store(o, &oq[512 + tid]);
    }
}

extern "C" void kernel_launch(void* const* d_in, const int* in_sizes, int n_in,
                              void* d_out, int out_size, void* d_ws, size_t ws_size,
                              hipStream_t stream) {
    const float* x  = (const float*)d_in[0];   // (M, N)
    const float* ws = (const float*)d_in[1];   // (N,)  -- only [0] used by ref
    const float* as = (const float*)d_in[2];   // (M, 1)
    const float* qs = (const float*)d_in[3];   // (1,)

    float* out_q     = (float*)d_out;                       // M*H
    float* out_scale = out_q + (size_t)M_ROWS * H_COLS;     // M

    swiglu_quant_kernel<<<dim3(M_ROWS / 2), dim3(512), 0, stream>>>(
        x, ws, as, qs, out_q, out_scale);
}